// Round 5
// baseline (698.872 us; speedup 1.0000x reference)
//
#include <hip/hip_runtime.h>

// Point2DirSum — R5: MEASUREMENT ROUND (deliberate).
// Three structurally different kernels (LDS-phased R1, streaming R3,
// contiguous-store R4) all plateau at ~265 us (~2.5 TB/s effective) while
// the harness fill proves 6.3 TB/s. All pipe models fail by >2x, and our
// kernel has NEVER appeared in the rocprof top-5 (fills at ~343 us mask
// it), so its FETCH/WRITE/VALUBusy/Occupancy have never been observed.
//
// This round runs the best kernel (R3) at 2x grid with the second half
// duplicating the first (bid = blockIdx.x & 8191). Both copies compute and
// store byte-identical values -> idempotent, correctness preserved,
// absmax stays 0 -- but the dispatch lasts ~530 us and surfaces in the
// top-5 WITH counters. Decision table:
//   WRITE_SIZE >> 1.07 GB  -> write amplification (spill/partial-line)
//   FETCH_SIZE >> 0.30 GB  -> read amplification
//   VALUBusy > 60%         -> VALU-bound codegen
//   Occupancy <= 15%       -> latency-bound, raise occupancy
//   all clean              -> mixed-stream BW ceiling is real => roofline.

typedef float f32x4 __attribute__((ext_vector_type(4)));

constexpr int N = 128, C = 16, H = 128, W = 128;
constexpr int TH = 32;               // output rows per block
constexpr int VB = 4;                // output rows per thread
constexpr int REAL_BLOCKS = N * C * (H / TH);        // 8192
constexpr int DUP = 2;               // work duplication factor (measurement)

__global__ __launch_bounds__(256, 4)
void Point2DirSum_kernel(const float* __restrict__ in, float* __restrict__ out) {
    const int tid = threadIdx.x;
    const int bid = blockIdx.x & (REAL_BLOCKS - 1);  // duplicate halves
    constexpr int TILES_PER_IMG = H / TH;            // 4
    const int img = bid / TILES_PER_IMG;             // n*C + c
    const int t   = bid % TILES_PER_IMG;
    const int h0  = t * TH;

    // Thread -> output patch: rows hb..hb+3, cols w4..w4+3.
    const int w4 = (tid & 31) * 4;
    const int hb = h0 + (tid >> 5) * VB;

    const float* __restrict__ base =
        in + (size_t)img * H * W + (size_t)(hb - 2) * W + (w4 - 2);

    const bool c_lo = (w4 != 0);         // cols w4-2,w4-1 valid?
    const bool c_hi = (w4 != W - 4);     // cols w4+4,w4+5 valid?

    float ve[VB][4], di[VB][4], ad[VB][4], ho[VB][4];
    #pragma unroll
    for (int i = 0; i < VB; ++i)
        #pragma unroll
        for (int j = 0; j < 4; ++j) { ve[i][j] = 0.f; di[i][j] = 0.f; ad[i][j] = 0.f; }

    #pragma unroll
    for (int r = 0; r < VB + 4; ++r) {           // input row = hb-2+r
        const int gr = hb - 2 + r;
        const bool rok = (unsigned)gr < (unsigned)H;  // zero-pad rows
        float e[8];
        #pragma unroll
        for (int k = 0; k < 8; ++k) e[k] = 0.f;
        if (rok) {
            const float* rp = base + r * W;
            const float4 m = *(const float4*)(rp + 2);   // cols w4..w4+3
            e[2] = m.x; e[3] = m.y; e[4] = m.z; e[5] = m.w;
            if (c_lo) { const float2 lo = *(const float2*)(rp);     e[0] = lo.x; e[1] = lo.y; }
            if (c_hi) { const float2 hi = *(const float2*)(rp + 6); e[6] = hi.x; e[7] = hi.y; }
        }
        #pragma unroll
        for (int i = 0; i < VB; ++i) {
            const int d = r - i;
            if (d >= 0 && d < 5) {
                #pragma unroll
                for (int j = 0; j < 4; ++j) {
                    ve[i][j] += e[j + 2];
                    di[i][j] += e[j + d];
                    ad[i][j] += e[j + 4 - d];
                }
                if (d == 2) {
                    #pragma unroll
                    for (int j = 0; j < 4; ++j)
                        ho[i][j] = e[j] + e[j + 1] + e[j + 2] + e[j + 3] + e[j + 4];
                }
            }
        }
    }

    const int n = img / C;
    const int c = img - n * C;
    float* __restrict__ outp = out + (((size_t)n * 4 * C + c) * (size_t)H) * W;
    const size_t plane = (size_t)C * H * W;          // stride between dir blocks

    #pragma unroll
    for (int i = 0; i < VB; ++i) {
        const size_t o = (size_t)(hb + i) * W + w4;
        f32x4 vho = { ho[i][0], ho[i][1], ho[i][2], ho[i][3] };
        f32x4 vve = { ve[i][0], ve[i][1], ve[i][2], ve[i][3] };
        f32x4 vdi = { di[i][0], di[i][1], di[i][2], di[i][3] };
        f32x4 vad = { ad[i][0], ad[i][1], ad[i][2], ad[i][3] };
        __builtin_nontemporal_store(vho, (f32x4*)&outp[o]);
        __builtin_nontemporal_store(vve, (f32x4*)&outp[o + plane]);
        __builtin_nontemporal_store(vdi, (f32x4*)&outp[o + 2 * plane]);
        __builtin_nontemporal_store(vad, (f32x4*)&outp[o + 3 * plane]);
    }
}

extern "C" void kernel_launch(void* const* d_in, const int* in_sizes, int n_in,
                              void* d_out, int out_size, void* d_ws, size_t ws_size,
                              hipStream_t stream) {
    const float* in = (const float*)d_in[0];
    float* out = (float*)d_out;
    const int grid = REAL_BLOCKS * DUP;              // 16384 blocks (2x dup)
    Point2DirSum_kernel<<<grid, 256, 0, stream>>>(in, out);
}